// Round 13
// baseline (150.945 us; speedup 1.0000x reference)
//
#include <hip/hip_runtime.h>
#include <hip/hip_bf16.h>
#include <stdint.h>

typedef __attribute__((ext_vector_type(8))) short short8;
typedef __attribute__((ext_vector_type(4))) float f32x4;

union FragU { short8 s; __hip_bfloat162 h[4]; };
union BU { uint4 u; short8 s; };

__device__ __forceinline__ unsigned short f2bf(float f) {
  union { float f; unsigned int u; } v; v.f = f;
  unsigned int r = v.u + 0x7fffu + ((v.u >> 16) & 1u);
  return (unsigned short)(r >> 16);
}
__device__ __forceinline__ float bf2f(unsigned short h) {
  union { unsigned int u; float f; } v; v.u = ((unsigned int)h) << 16;
  return v.f;
}

// async global -> LDS, 16B per lane. LDS dest = uniform base + lane*16 (linear).
#define GLOAD_LDS16(gp, lp) \
  __builtin_amdgcn_global_load_lds((const __attribute__((address_space(1))) void*)(gp), \
                                   (__attribute__((address_space(3))) void*)(lp), 16, 0, 0)

// ---------------------------------------------------------------------------
// Kernel 0: bTf = relGW (= rel @ GW) packed in MFMA-fragment order per 64-k
// tile: tile tt (8KB) holds 16B frags indexed f = nt*128 + kc*64 + lane,
// frag(nt,kc,lane=(g,r)) = bf16{ relGW[tt*64 + kc*32 + g*8 + s][nt*16 + r] }.
// Also zeros the 1024-float accumulator region.  grid 64 x 256
// ---------------------------------------------------------------------------
__global__ void k_prep(const float* __restrict__ rel, const float* __restrict__ GW,
                       unsigned short* __restrict__ bTf, float* __restrict__ accums) {
  __shared__ float tile[64][65];   // rel rows j*64..+63   [k][i]
  __shared__ float gws[64][64];    // GW [i][e]
  __shared__ float relgw[64][64];  // (rel@GW)[k][e] for this k-block
  const int j = blockIdx.x;
  const int t = threadIdx.x;
#pragma unroll
  for (int p = 0; p < 16; ++p) {
    int elem = p * 256 + t;
    int kk = elem >> 6, ee = elem & 63;
    tile[kk][ee] = rel[(j * 64 + kk) * 64 + ee];
    ((float*)gws)[elem] = GW[elem];
  }
  __syncthreads();
  {
    const int e = t >> 2, chunk = t & 3;
    for (int i = 0; i < 16; ++i) {
      float acc = 0.f;
#pragma unroll
      for (int ii = 0; ii < 64; ++ii) acc += tile[chunk * 16 + i][ii] * gws[ii][e];
      relgw[chunk * 16 + i][e] = acc;
    }
  }
  __syncthreads();
  // pack fragments: thread t writes frags f = 2t, 2t+1
#pragma unroll
  for (int m = 0; m < 2; ++m) {
    const int f = t * 2 + m;
    const int nt = f >> 7, kc = (f >> 6) & 1, ln = f & 63;
    const int g = ln >> 4, r = ln & 15;
    union { unsigned short u16[8]; uint4 v; } pk;
#pragma unroll
    for (int s = 0; s < 8; ++s) pk.u16[s] = f2bf(relgw[kc * 32 + g * 8 + s][nt * 16 + r]);
    *(uint4*)(bTf + (size_t)j * 4096 + f * 8) = pk.v;
  }
  if (j == 0) {
    accums[t] = 0.f; accums[t + 256] = 0.f; accums[t + 512] = 0.f; accums[t + 768] = 0.f;
  }
}

// ---------------------------------------------------------------------------
// Fused main kernel, 256-thread blocks.
//   blocks 0..15    : tree attention (4 trees per block, one per wave)
//   blocks 16..527  : GEMM  C = link[b][64 rows] @ relGW  (K=4096, cols=64)
//     BARRIER-FREE per-wave pipeline: wave owns 16 rows x full K.
//     A: global_load_lds into wave-private 2x4KB LDS ring.
//     B: fragment-packed bTf, DOUBLE-BUFFERED in registers (bq0/bq1),
//        prefetched one full tile ahead.  Steady state: vmcnt(12) ->
//        COMPUTE(t) -> STAGEA(t+2)+LOADB(t+2); vmcnt never drains in-loop.
// ---------------------------------------------------------------------------
__global__ __launch_bounds__(256, 2) void k_main(
    const float* __restrict__ link, const unsigned short* __restrict__ bTf,
    const float* __restrict__ gbias, float* __restrict__ pooled_sum,
    const float* __restrict__ col_table, const float* __restrict__ rel_table,
    const float* __restrict__ Wk, const float* __restrict__ Wq, const float* __restrict__ Wv,
    const int* __restrict__ table_ids, const int* __restrict__ l_ids,
    const int* __restrict__ r_ids, float* __restrict__ tree_emb) {
  __shared__ union {
    struct { char a[4][2][4096]; } g;                                // 32 KB
    struct { unsigned short W3b[3 * 4096]; float qT[4][64][4]; } tr; // 28 KB
  } sm;

  const int t = threadIdx.x;
  const int lane = t & 63;
  const int wid = t >> 6;            // 0..3

  if (blockIdx.x >= 16) {
    // ------------------ GEMM branch (independent wave pipelines) ------------
    const int gid = blockIdx.x - 16;          // 0..511
    const int b = gid >> 6;                   // batch
    const int rb = gid & 63;                  // 64-row block
    const int rowG0 = rb * 64 + wid * 16;     // this wave's first row
    const int phase = (gid * 4 + wid + b * 9) & 63;
    const int g = lane >> 4;                  // k-group 0..3
    const int r = lane & 15;                  // row/col within fragment
    const uint32_t fr = (uint32_t)((r & 7) << 4);

    const char* linkb = (const char*)(link + ((size_t)b << 24));
    const char* bTfb = (const char*)bTf;
    const int a_ri = lane >> 4;               // row within A stage instr
    const uint32_t a_cb = (uint32_t)((lane & 15) * 16);

    char* a0buf = sm.g.a[wid][0];
    char* a1buf = sm.g.a[wid][1];

    f32x4 acc[4];
#pragma unroll
    for (int nt = 0; nt < 4; ++nt) acc[nt] = (f32x4){0.f, 0.f, 0.f, 0.f};
    uint4 bq0[8], bq1[8];

#define STAGEA(ab_, tta) do {                                              \
    const size_t ka = (size_t)(tta) * 256;                                 \
    _Pragma("unroll")                                                      \
    for (int j = 0; j < 4; ++j) {                                          \
      const int wlrow = 4 * j + a_ri;                                      \
      const uint32_t cb = a_cb ^ ((uint32_t)(wlrow & 7) << 4);             \
      GLOAD_LDS16(linkb + (size_t)(rowG0 + wlrow) * 16384 + ka + cb,       \
                  (ab_) + j * 1024);                                       \
    }                                                                      \
  } while (0)

#define LOADB(bq_, tta) do {                                               \
    const char* bb = bTfb + (size_t)(tta) * 8192 + lane * 16;              \
    _Pragma("unroll")                                                      \
    for (int j = 0; j < 8; ++j) bq_[j] = *(const uint4*)(bb + j * 1024);   \
  } while (0)

#define COMPUTEW(ab_, bq_) do {                                            \
    const char* ar = (ab_) + r * 256;                                      \
    _Pragma("unroll")                                                      \
    for (int kc = 0; kc < 2; ++kc) {                                       \
      const uint32_t o0 = ((uint32_t)(kc * 128 + g * 32)) ^ fr;            \
      const f32x4 a0 = *(const f32x4*)(ar + o0);                           \
      const f32x4 a1 = *(const f32x4*)(ar + (o0 ^ 16));                    \
      FragU f;                                                             \
      f.h[0] = __float22bfloat162_rn(float2{a0[0], a0[1]});                \
      f.h[1] = __float22bfloat162_rn(float2{a0[2], a0[3]});                \
      f.h[2] = __float22bfloat162_rn(float2{a1[0], a1[1]});                \
      f.h[3] = __float22bfloat162_rn(float2{a1[2], a1[3]});                \
      _Pragma("unroll")                                                    \
      for (int nt = 0; nt < 4; ++nt) {                                     \
        BU bu; bu.u = bq_[nt * 2 + kc];                                    \
        acc[nt] = __builtin_amdgcn_mfma_f32_16x16x32_bf16(f.s, bu.s, acc[nt], 0, 0, 0); \
      }                                                                    \
    }                                                                      \
  } while (0)

    // prologue: tiles 0 and 1 fully in flight (24 VMEM ops)
    STAGEA(a0buf, phase);
    LOADB(bq0, phase);
    STAGEA(a1buf, (phase + 1) & 63);
    LOADB(bq1, (phase + 1) & 63);

    for (int it2 = 0; it2 < 32; ++it2) {
      const int te = 2 * it2;
      // even tile -> buf0/bq0
      asm volatile("s_waitcnt vmcnt(12)" ::: "memory");  // tile te done; te+1 in flight
      COMPUTEW(a0buf, bq0);
      if (it2 < 31) {
        STAGEA(a0buf, (te + 2 + phase) & 63);
        LOADB(bq0, (te + 2 + phase) & 63);
      }
      // odd tile -> buf1/bq1
      if (it2 < 31) { asm volatile("s_waitcnt vmcnt(12)" ::: "memory"); }
      else          { asm volatile("s_waitcnt vmcnt(0)"  ::: "memory"); }
      COMPUTEW(a1buf, bq1);
      if (it2 < 31) {
        STAGEA(a1buf, (te + 3 + phase) & 63);
        LOADB(bq1, (te + 3 + phase) & 63);
      }
    }

    // ---- epilogue: relu(C + bias) colsum over this wave's 16 rows ----
#pragma unroll
    for (int nt = 0; nt < 4; ++nt) {
      const float gbv = gbias[nt * 16 + r];
      float s = 0.f;
#pragma unroll
      for (int j = 0; j < 4; ++j) s += fmaxf(acc[nt][j] + gbv, 0.f);
      s += __shfl_xor(s, 16);
      s += __shfl_xor(s, 32);
      if (g == 0) atomicAdd(&pooled_sum[b * 64 + nt * 16 + r], s);
    }
  } else {
    // ------------------------- tree branch ----------------------------------
    const int e = lane;
    for (int i = t; i < 3 * 4096; i += 256) {
      float v;
      if (i < 4096) v = Wk[i];
      else if (i < 8192) v = Wq[i - 4096];
      else v = Wv[i - 8192];
      sm.tr.W3b[i] = f2bf(v);
    }
    __syncthreads();

    const int tree = blockIdx.x * 4 + wid;   // 0..63
    const int b = tree >> 3;
    const int* tid = table_ids + tree * 17;
    const int* lid = l_ids + tree * 32;
    const int* rid = r_ids + tree * 32;

    float prev = rel_table[tid[0] * 64 + e];

    for (int d = 0; d < 16; ++d) {
      const int l0 = lid[d * 2], l1 = lid[d * 2 + 1];
      const int r0 = rid[d * 2], r1 = rid[d * 2 + 1];
      const float lce = 0.5f * (col_table[l0 * 64 + e] + col_table[l1 * 64 + e]);
      const float rce = 0.5f * (col_table[r0 * 64 + e] + col_table[r1 * 64 + e]);
      const float rte = rel_table[tid[1 + d] * 64 + e];
      float4 qv0; qv0.x = prev; qv0.y = lce; qv0.z = rce; qv0.w = rte;
      *(float4*)&sm.tr.qT[wid][e][0] = qv0;
      __syncthreads();

      float K[4] = {0, 0, 0, 0}, Q[4] = {0, 0, 0, 0}, V[4] = {0, 0, 0, 0};
#pragma unroll 8
      for (int i = 0; i < 64; ++i) {
        const f32x4 qv = *(const f32x4*)&sm.tr.qT[wid][i][0];
        const float wk = bf2f(sm.tr.W3b[i * 64 + e]);
        const float wq = bf2f(sm.tr.W3b[4096 + i * 64 + e]);
        const float wvv = bf2f(sm.tr.W3b[8192 + i * 64 + e]);
#pragma unroll
        for (int j = 0; j < 4; ++j) {
          K[j] += qv[j] * wk;
          Q[j] += qv[j] * wq;
          V[j] += qv[j] * wvv;
        }
      }

      float sc[4][4];
#pragma unroll
      for (int j = 0; j < 4; ++j)
#pragma unroll
        for (int k = 0; k < 4; ++k) {
          float p = Q[j] * K[k];
          p += __shfl_xor(p, 1);  p += __shfl_xor(p, 2);  p += __shfl_xor(p, 4);
          p += __shfl_xor(p, 8);  p += __shfl_xor(p, 16); p += __shfl_xor(p, 32);
          sc[j][k] = p * (1.f / 64.f);
        }

      float wsum[4] = {0, 0, 0, 0};
#pragma unroll
      for (int j = 0; j < 4; ++j) {
        float mx = fmaxf(fmaxf(sc[j][0], sc[j][1]), fmaxf(sc[j][2], sc[j][3]));
        float a0 = __expf(sc[j][0] - mx), a1 = __expf(sc[j][1] - mx);
        float a2 = __expf(sc[j][2] - mx), a3 = __expf(sc[j][3] - mx);
        float inv = 1.f / (a0 + a1 + a2 + a3);
        wsum[0] += a0 * inv; wsum[1] += a1 * inv; wsum[2] += a2 * inv; wsum[3] += a3 * inv;
      }

      prev = wsum[0] * V[0] + wsum[1] * V[1] + wsum[2] * V[2] + wsum[3] * V[3];
      __syncthreads();
    }
    atomicAdd(&tree_emb[b * 64 + e], prev);
  }
}

// ---------------------------------------------------------------------------
// Kernel 2: logits = [pooled_sum/4096 || tree_emb] @ fc_w  + clip(log(mask))
// grid 128 x 256
// ---------------------------------------------------------------------------
__global__ void k_final(const float* __restrict__ action_mask, const float* __restrict__ fc_w,
                        const float* __restrict__ pooled_sum, const float* __restrict__ tree_emb,
                        float* __restrict__ out) {
  __shared__ float c[128];
  const int b = blockIdx.x >> 4;
  const int a = ((blockIdx.x & 15) << 8) + threadIdx.x;
  if (threadIdx.x < 128) {
    c[threadIdx.x] = (threadIdx.x < 64) ? pooled_sum[b * 64 + threadIdx.x] * (1.f / 4096.f)
                                        : tree_emb[b * 64 + threadIdx.x - 64];
  }
  __syncthreads();
  float acc = 0.f;
  for (int i = 0; i < 128; ++i) acc += c[i] * fc_w[i * 4096 + a];
  const float m = action_mask[b * 4096 + a];
  float lg = __logf(m);
  lg = fminf(fmaxf(lg, -3.4e38f), 3.4e38f);
  out[b * 4096 + a] = lg + acc;
}

// ---------------------------------------------------------------------------
extern "C" void kernel_launch(void* const* d_in, const int* in_sizes, int n_in,
                              void* d_out, int out_size, void* d_ws, size_t ws_size,
                              hipStream_t stream) {
  const float* link = (const float*)d_in[0];
  const float* mask = (const float*)d_in[1];
  const float* col = (const float*)d_in[2];
  const float* rel = (const float*)d_in[3];
  const float* GW = (const float*)d_in[4];
  const float* gb = (const float*)d_in[5];
  const float* Wk = (const float*)d_in[6];
  const float* Wq = (const float*)d_in[7];
  const float* Wv = (const float*)d_in[8];
  const float* fcw = (const float*)d_in[9];
  const int* tids = (const int*)d_in[10];
  const int* lids = (const int*)d_in[11];
  const int* rids = (const int*)d_in[12];
  float* out = (float*)d_out;

  unsigned short* bTf = (unsigned short*)d_ws;              // 512 KB (frag-packed relGW)
  float* accums = (float*)((char*)d_ws + 512 * 1024);       // 1024 floats
  float* pooled_sum = accums;                               // [8][64]
  float* tree = accums + 512;                               // [8][64]

  hipLaunchKernelGGL(k_prep, dim3(64), dim3(256), 0, stream, rel, GW, bTf, accums);
  hipLaunchKernelGGL(k_main, dim3(528), dim3(256), 0, stream,
                     link, bTf, gb, pooled_sum,
                     col, rel, Wk, Wq, Wv, tids, lids, rids, tree);
  hipLaunchKernelGGL(k_final, dim3(128), dim3(256), 0, stream, mask, fcw, pooled_sum, tree, out);
}

// Round 14
// 142.880 us; speedup vs baseline: 1.0564x; 1.0564x over previous
//
#include <hip/hip_runtime.h>
#include <hip/hip_bf16.h>
#include <stdint.h>

typedef __attribute__((ext_vector_type(8))) short short8;
typedef __attribute__((ext_vector_type(4))) float f32x4;

union FragU { short8 s; __hip_bfloat162 h[4]; };
union BU { uint4 u; short8 s; };

__device__ __forceinline__ unsigned short f2bf(float f) {
  union { float f; unsigned int u; } v; v.f = f;
  unsigned int r = v.u + 0x7fffu + ((v.u >> 16) & 1u);
  return (unsigned short)(r >> 16);
}
__device__ __forceinline__ float bf2f(unsigned short h) {
  union { unsigned int u; float f; } v; v.u = ((unsigned int)h) << 16;
  return v.f;
}

// async global -> LDS, 16B per lane. LDS dest = uniform base + lane*16 (linear).
#define GLOAD_LDS16(gp, lp) \
  __builtin_amdgcn_global_load_lds((const __attribute__((address_space(1))) void*)(gp), \
                                   (__attribute__((address_space(3))) void*)(lp), 16, 0, 0)

// ---------------------------------------------------------------------------
// Kernel 0: bTf = relGW (= rel @ GW) packed in MFMA-fragment order per 64-k
// tile: tile tt (8KB) holds 16B frags indexed f = nt*128 + kc*64 + lane,
// frag(nt,kc,lane=(g,r)) = bf16{ relGW[tt*64 + kc*32 + g*8 + s][nt*16 + r] }.
// Also zeros the 1024-float accumulator region.  grid 64 x 256
// ---------------------------------------------------------------------------
__global__ void k_prep(const float* __restrict__ rel, const float* __restrict__ GW,
                       unsigned short* __restrict__ bTf, float* __restrict__ accums) {
  __shared__ float tile[64][65];   // rel rows j*64..+63   [k][i]
  __shared__ float gws[64][64];    // GW [i][e]
  __shared__ float relgw[64][64];  // (rel@GW)[k][e] for this k-block
  const int j = blockIdx.x;
  const int t = threadIdx.x;
#pragma unroll
  for (int p = 0; p < 16; ++p) {
    int elem = p * 256 + t;
    int kk = elem >> 6, ee = elem & 63;
    tile[kk][ee] = rel[(j * 64 + kk) * 64 + ee];
    ((float*)gws)[elem] = GW[elem];
  }
  __syncthreads();
  {
    const int e = t >> 2, chunk = t & 3;
    for (int i = 0; i < 16; ++i) {
      float acc = 0.f;
#pragma unroll
      for (int ii = 0; ii < 64; ++ii) acc += tile[chunk * 16 + i][ii] * gws[ii][e];
      relgw[chunk * 16 + i][e] = acc;
    }
  }
  __syncthreads();
  // pack fragments: thread t writes frags f = 2t, 2t+1
#pragma unroll
  for (int m = 0; m < 2; ++m) {
    const int f = t * 2 + m;
    const int nt = f >> 7, kc = (f >> 6) & 1, ln = f & 63;
    const int g = ln >> 4, r = ln & 15;
    union { unsigned short u16[8]; uint4 v; } pk;
#pragma unroll
    for (int s = 0; s < 8; ++s) pk.u16[s] = f2bf(relgw[kc * 32 + g * 8 + s][nt * 16 + r]);
    *(uint4*)(bTf + (size_t)j * 4096 + f * 8) = pk.v;
  }
  if (j == 0) {
    accums[t] = 0.f; accums[t + 256] = 0.f; accums[t + 512] = 0.f; accums[t + 768] = 0.f;
  }
}

// ---------------------------------------------------------------------------
// Fused main kernel, 256-thread blocks.
//   blocks 0..15    : tree attention (4 trees per block, one per wave)
//   blocks 16..527  : GEMM  C = link[b][64 rows] @ relGW  (K=4096, cols=64)
//     BARRIER-FREE per-wave pipeline, BK=128 (512B DRAM runs per row visit —
//     2x the run length of BK=64, halving row-activation rate).
//     A: 8 global_load_lds/tile into wave-private 2x8KB LDS ring.
//     B: fragment-packed bTf to registers (16 uint4), single-buffered.
//     Steady: LOADB(t) -> STAGEA(t+1) -> vmcnt(8) -> COMPUTE(t).
// ---------------------------------------------------------------------------
__global__ __launch_bounds__(256, 2) void k_main(
    const float* __restrict__ link, const unsigned short* __restrict__ bTf,
    const float* __restrict__ gbias, float* __restrict__ pooled_sum,
    const float* __restrict__ col_table, const float* __restrict__ rel_table,
    const float* __restrict__ Wk, const float* __restrict__ Wq, const float* __restrict__ Wv,
    const int* __restrict__ table_ids, const int* __restrict__ l_ids,
    const int* __restrict__ r_ids, float* __restrict__ tree_emb) {
  __shared__ union {
    struct { char a[4][2][8192]; } g;                                // 64 KB
    struct { unsigned short W3b[3 * 4096]; float qT[4][64][4]; } tr; // 28 KB
  } sm;

  const int t = threadIdx.x;
  const int lane = t & 63;
  const int wid = t >> 6;            // 0..3

  if (blockIdx.x >= 16) {
    // ------------------ GEMM branch (independent wave pipelines) ------------
    const int gid = blockIdx.x - 16;          // 0..511
    const int b = gid >> 6;                   // batch
    const int rb = gid & 63;                  // 64-row block
    const int rowG0 = rb * 64 + wid * 16;     // this wave's first row
    const int phase = (gid * 4 + wid + b * 9) & 31;   // 32 tiles of 128k
    const int g = lane >> 4;                  // k-group 0..3
    const int r = lane & 15;                  // row/col within fragment
    const uint32_t fr = (uint32_t)((r & 7) << 4);

    const char* linkb = (const char*)(link + ((size_t)b << 24));
    const char* bTfb = (const char*)bTf;
    // A stage instr j covers rows 2j,2j+1: lane l -> row 2j+(l>>5),
    // within-row byte ((l&31)*16) ^ ((row&7)<<4)  (512B contiguous per row)
    const int a_r2 = lane >> 5;                       // 0..1
    const uint32_t a_wb = (uint32_t)((lane & 31) * 16);

    char* a0buf = sm.g.a[wid][0];
    char* a1buf = sm.g.a[wid][1];

    f32x4 acc[4];
#pragma unroll
    for (int nt = 0; nt < 4; ++nt) acc[nt] = (f32x4){0.f, 0.f, 0.f, 0.f};
    uint4 bq[16];

#define STAGEA(ab_, tta) do {                                              \
    const size_t ka = (size_t)(tta) * 512;  /* 128k * 4B per row */        \
    _Pragma("unroll")                                                      \
    for (int j = 0; j < 8; ++j) {                                          \
      const int wlrow = 2 * j + a_r2;                                      \
      const uint32_t cb = a_wb ^ ((uint32_t)(wlrow & 7) << 4);             \
      GLOAD_LDS16(linkb + (size_t)(rowG0 + wlrow) * 16384 + ka + cb,       \
                  (ab_) + j * 1024);                                       \
    }                                                                      \
  } while (0)

#define LOADB(tta) do {                                                    \
    const char* bb = bTfb + (size_t)(tta) * 16384 + lane * 16;             \
    _Pragma("unroll")                                                      \
    for (int j = 0; j < 8; ++j) {                                          \
      bq[j]     = *(const uint4*)(bb + j * 1024);                          \
      bq[8 + j] = *(const uint4*)(bb + 8192 + j * 1024);                   \
    }                                                                      \
  } while (0)

#define COMPUTEW(ab_) do {                                                 \
    const char* ar = (ab_) + r * 512;                                      \
    _Pragma("unroll")                                                      \
    for (int kh = 0; kh < 2; ++kh) {                                       \
      _Pragma("unroll")                                                    \
      for (int kc = 0; kc < 2; ++kc) {                                     \
        const uint32_t o0 = ((uint32_t)(kh * 256 + kc * 128 + g * 32)) ^ fr; \
        const f32x4 a0 = *(const f32x4*)(ar + o0);                         \
        const f32x4 a1 = *(const f32x4*)(ar + (o0 ^ 16));                  \
        FragU f;                                                           \
        f.h[0] = __float22bfloat162_rn(float2{a0[0], a0[1]});              \
        f.h[1] = __float22bfloat162_rn(float2{a0[2], a0[3]});              \
        f.h[2] = __float22bfloat162_rn(float2{a1[0], a1[1]});              \
        f.h[3] = __float22bfloat162_rn(float2{a1[2], a1[3]});              \
        _Pragma("unroll")                                                  \
        for (int nt = 0; nt < 4; ++nt) {                                   \
          BU bu; bu.u = bq[kh * 8 + nt * 2 + kc];                          \
          acc[nt] = __builtin_amdgcn_mfma_f32_16x16x32_bf16(f.s, bu.s, acc[nt], 0, 0, 0); \
        }                                                                  \
      }                                                                    \
    }                                                                      \
  } while (0)

    STAGEA(a0buf, phase);                  // tile 0 into buf0
    for (int it2 = 0; it2 < 16; ++it2) {
      const int te = 2 * it2;
      // even tile -> buf0
      LOADB((te + phase) & 31);
      STAGEA(a1buf, (te + 1 + phase) & 31);
      asm volatile("s_waitcnt vmcnt(8)" ::: "memory");   // A(te),B(te) done; A(te+1) in flight
      COMPUTEW(a0buf);
      // odd tile -> buf1
      LOADB((te + 1 + phase) & 31);
      if (it2 < 15) {
        STAGEA(a0buf, (te + 2 + phase) & 31);
        asm volatile("s_waitcnt vmcnt(8)" ::: "memory");
      } else {
        asm volatile("s_waitcnt vmcnt(0)" ::: "memory");
      }
      COMPUTEW(a1buf);
    }

    // ---- epilogue: relu(C + bias) colsum over this wave's 16 rows ----
#pragma unroll
    for (int nt = 0; nt < 4; ++nt) {
      const float gbv = gbias[nt * 16 + r];
      float s = 0.f;
#pragma unroll
      for (int j = 0; j < 4; ++j) s += fmaxf(acc[nt][j] + gbv, 0.f);
      s += __shfl_xor(s, 16);
      s += __shfl_xor(s, 32);
      if (g == 0) atomicAdd(&pooled_sum[b * 64 + nt * 16 + r], s);
    }
  } else {
    // ------------------------- tree branch ----------------------------------
    const int e = lane;
    for (int i = t; i < 3 * 4096; i += 256) {
      float v;
      if (i < 4096) v = Wk[i];
      else if (i < 8192) v = Wq[i - 4096];
      else v = Wv[i - 8192];
      sm.tr.W3b[i] = f2bf(v);
    }
    __syncthreads();

    const int tree = blockIdx.x * 4 + wid;   // 0..63
    const int b = tree >> 3;
    const int* tid = table_ids + tree * 17;
    const int* lid = l_ids + tree * 32;
    const int* rid = r_ids + tree * 32;

    float prev = rel_table[tid[0] * 64 + e];

    for (int d = 0; d < 16; ++d) {
      const int l0 = lid[d * 2], l1 = lid[d * 2 + 1];
      const int r0 = rid[d * 2], r1 = rid[d * 2 + 1];
      const float lce = 0.5f * (col_table[l0 * 64 + e] + col_table[l1 * 64 + e]);
      const float rce = 0.5f * (col_table[r0 * 64 + e] + col_table[r1 * 64 + e]);
      const float rte = rel_table[tid[1 + d] * 64 + e];
      float4 qv0; qv0.x = prev; qv0.y = lce; qv0.z = rce; qv0.w = rte;
      *(float4*)&sm.tr.qT[wid][e][0] = qv0;
      __syncthreads();

      float K[4] = {0, 0, 0, 0}, Q[4] = {0, 0, 0, 0}, V[4] = {0, 0, 0, 0};
#pragma unroll 8
      for (int i = 0; i < 64; ++i) {
        const f32x4 qv = *(const f32x4*)&sm.tr.qT[wid][i][0];
        const float wk = bf2f(sm.tr.W3b[i * 64 + e]);
        const float wq = bf2f(sm.tr.W3b[4096 + i * 64 + e]);
        const float wvv = bf2f(sm.tr.W3b[8192 + i * 64 + e]);
#pragma unroll
        for (int j = 0; j < 4; ++j) {
          K[j] += qv[j] * wk;
          Q[j] += qv[j] * wq;
          V[j] += qv[j] * wvv;
        }
      }

      float sc[4][4];
#pragma unroll
      for (int j = 0; j < 4; ++j)
#pragma unroll
        for (int k = 0; k < 4; ++k) {
          float p = Q[j] * K[k];
          p += __shfl_xor(p, 1);  p += __shfl_xor(p, 2);  p += __shfl_xor(p, 4);
          p += __shfl_xor(p, 8);  p += __shfl_xor(p, 16); p += __shfl_xor(p, 32);
          sc[j][k] = p * (1.f / 64.f);
        }

      float wsum[4] = {0, 0, 0, 0};
#pragma unroll
      for (int j = 0; j < 4; ++j) {
        float mx = fmaxf(fmaxf(sc[j][0], sc[j][1]), fmaxf(sc[j][2], sc[j][3]));
        float a0 = __expf(sc[j][0] - mx), a1 = __expf(sc[j][1] - mx);
        float a2 = __expf(sc[j][2] - mx), a3 = __expf(sc[j][3] - mx);
        float inv = 1.f / (a0 + a1 + a2 + a3);
        wsum[0] += a0 * inv; wsum[1] += a1 * inv; wsum[2] += a2 * inv; wsum[3] += a3 * inv;
      }

      prev = wsum[0] * V[0] + wsum[1] * V[1] + wsum[2] * V[2] + wsum[3] * V[3];
      __syncthreads();
    }
    atomicAdd(&tree_emb[b * 64 + e], prev);
  }
}

// ---------------------------------------------------------------------------
// Kernel 2: logits = [pooled_sum/4096 || tree_emb] @ fc_w  + clip(log(mask))
// grid 128 x 256
// ---------------------------------------------------------------------------
__global__ void k_final(const float* __restrict__ action_mask, const float* __restrict__ fc_w,
                        const float* __restrict__ pooled_sum, const float* __restrict__ tree_emb,
                        float* __restrict__ out) {
  __shared__ float c[128];
  const int b = blockIdx.x >> 4;
  const int a = ((blockIdx.x & 15) << 8) + threadIdx.x;
  if (threadIdx.x < 128) {
    c[threadIdx.x] = (threadIdx.x < 64) ? pooled_sum[b * 64 + threadIdx.x] * (1.f / 4096.f)
                                        : tree_emb[b * 64 + threadIdx.x - 64];
  }
  __syncthreads();
  float acc = 0.f;
  for (int i = 0; i < 128; ++i) acc += c[i] * fc_w[i * 4096 + a];
  const float m = action_mask[b * 4096 + a];
  float lg = __logf(m);
  lg = fminf(fmaxf(lg, -3.4e38f), 3.4e38f);
  out[b * 4096 + a] = lg + acc;
}

// ---------------------------------------------------------------------------
extern "C" void kernel_launch(void* const* d_in, const int* in_sizes, int n_in,
                              void* d_out, int out_size, void* d_ws, size_t ws_size,
                              hipStream_t stream) {
  const float* link = (const float*)d_in[0];
  const float* mask = (const float*)d_in[1];
  const float* col = (const float*)d_in[2];
  const float* rel = (const float*)d_in[3];
  const float* GW = (const float*)d_in[4];
  const float* gb = (const float*)d_in[5];
  const float* Wk = (const float*)d_in[6];
  const float* Wq = (const float*)d_in[7];
  const float* Wv = (const float*)d_in[8];
  const float* fcw = (const float*)d_in[9];
  const int* tids = (const int*)d_in[10];
  const int* lids = (const int*)d_in[11];
  const int* rids = (const int*)d_in[12];
  float* out = (float*)d_out;

  unsigned short* bTf = (unsigned short*)d_ws;              // 512 KB (frag-packed relGW)
  float* accums = (float*)((char*)d_ws + 512 * 1024);       // 1024 floats
  float* pooled_sum = accums;                               // [8][64]
  float* tree = accums + 512;                               // [8][64]

  hipLaunchKernelGGL(k_prep, dim3(64), dim3(256), 0, stream, rel, GW, bTf, accums);
  hipLaunchKernelGGL(k_main, dim3(528), dim3(256), 0, stream,
                     link, bTf, gb, pooled_sum,
                     col, rel, Wk, Wq, Wv, tids, lids, rids, tree);
  hipLaunchKernelGGL(k_final, dim3(128), dim3(256), 0, stream, mask, fcw, pooled_sum, tree, out);
}